// Round 8
// baseline (268.987 us; speedup 1.0000x reference)
//
#include <hip/hip_runtime.h>
#include <hip/hip_bf16.h>

// BatchedNLM: per-neuron 2-layer GLU MLP.
//   state_trace (128,2048,32) f32, fc1_w (2048,32,256), fc1_b (2048,256),
//   fc2_w (2048,128,2), fc2_b (2048,2), T (1)  ->  out (128,2048) f32
//
// R5 WIN (94->46): w1 via global_load_lds width=16 (async DMA, no VGPRs).
// R6 WIN (46->40): rcpf sigmoid + LDS alias (35 KB).
// R7 NEUTRAL: NPB=4 pipeline grew LDS to 55 KB -> 2 blocks/CU -> Occ 15%.
//     Implied block lifetime ~20 us vs ~6k cycles of work: blocks are ~7x
//     stalled and there are not enough waves to cover. Occupancy is the
//     binding constraint, not intra-block overlap.
// R8: TLP-max. 512-thread blocks (8 waves), ONE neuron/block, one 16-batch
//     m-tile per wave (halves per-wave register footprint). R6 aliasing keeps
//     LDS at 34.8 KB -> 4 blocks/CU = 32 waves/CU (full wave slots). Four
//     independent blocks per CU stagger fetch/compute phases naturally.
//     launch_bounds(512,6): VGPR cap ~85 = spill-proof headroom (R2 lesson);
//     expected natural allocation ~55-65 -> occupancy set by LDS.

#define NN 2048

typedef __attribute__((ext_vector_type(8))) short short8;
typedef __attribute__((ext_vector_type(4))) float floatx4;
typedef __attribute__((ext_vector_type(4))) int int4v;

static __device__ __forceinline__ unsigned int pkbf(float a, float b) {
    __hip_bfloat162 h = __float22bfloat162_rn(make_float2(a, b));  // v_cvt_pk_bf16_f32
    return *(unsigned int*)&h;
}

static __device__ __forceinline__ float sigmoidf(float x) {
    return __builtin_amdgcn_rcpf(1.0f + __expf(-x));   // no IEEE div sequence
}

static __device__ __forceinline__ void gload_lds16(const float* g, float* l) {
    // Per-lane gptr; LDS dest = wave-uniform base + lane*16B (m97/m104 semantics).
    __builtin_amdgcn_global_load_lds((const __attribute__((address_space(1))) void*)g,
                                     (__attribute__((address_space(3))) void*)l,
                                     16, 0, 0);
}

__global__ __launch_bounds__(512, 6)
void nlm_kernel(const float* __restrict__ st,
                const float* __restrict__ w1,
                const float* __restrict__ b1,
                const float* __restrict__ w2,
                const float* __restrict__ b2,
                const float* __restrict__ Tp,
                float* __restrict__ out_t)
{
    const int n = blockIdx.x;
    const int t = threadIdx.x;            // 0..511

    // ldsW: raw f32 W1[n] (32 KB). Its first 16 KB is reused as the bf16
    // fragment-major buffer after the register-held conversion pass.
    __shared__ __align__(16) float  ldsW[32 * 256];
    __shared__ float4 ldsP[128];          // {b1[h], b1[128+h], w2[2h], w2[2h+1]}
    __shared__ float  ldsO[128];
    short* ldsB = (short*)ldsW;

    const int lane = t & 63;
    const int wv   = t >> 6;      // wave 0..7; wave wv owns batches [16wv,16wv+16)
    const int m    = lane & 15;   // A row / C col
    const int quad = lane >> 4;   // k-quad / C row group

    // ---- 1) Async DMA: W1[n] (32 KB f32) -> ldsW. 4 instrs/wave, no VGPRs. ----
    {
        const float* gW = w1 + (size_t)n * 8192;
        #pragma unroll
        for (int i = 0; i < 4; ++i) {
            const int off = (i * 8 + wv) * 256;       // floats, wave-uniform
            gload_lds16(gW + off + lane * 4, &ldsW[off]);
        }
    }

    // ---- 2) Register loads behind the DMA: A-frag (1 m-tile/wave) + params ----
    floatx4 av0, av1;
    {
        const int b = wv * 16 + m;
        const float* sp = st + (size_t)b * (NN * 32) + (size_t)n * 32 + quad * 8;
        av0 = *(const floatx4*)sp;
        av1 = *(const floatx4*)(sp + 4);
    }

    float pba = 0.f, pbb = 0.f;
    float2 pw2 = make_float2(0.f, 0.f);
    if (t < 128) {
        const float* b1p = b1 + n * 256;
        const float* w2p = w2 + n * 256;
        pba = b1p[t];
        pbb = b1p[128 + t];
        pw2 = *(const float2*)(w2p + 2 * t);
    }

    const float bb0  = b2[n * 2 + 0];
    const float bb1  = b2[n * 2 + 1];
    const float invT = 1.0f / Tp[0];

    // Convert A-frag while DMA is in flight.
    short8 afrag;
    {
        union { int4v iv; short8 s; } u;
        u.iv[0] = pkbf(av0[0], av0[1]);
        u.iv[1] = pkbf(av0[2], av0[3]);
        u.iv[2] = pkbf(av1[0], av1[1]);
        u.iv[3] = pkbf(av1[2], av1[3]);
        afrag = u.s;
    }
    if (t < 128)
        ldsP[t] = make_float4(pba, pbb, pw2.x, pw2.y);

    __syncthreads();   // b1: DMA drained; ldsP visible

    // ---- 3) In-place conversion: 2 threads per column h; thread handles
    // k = half*16 .. half*16+15. Reads lane-consecutive (2-way alias = free).
    {
        const int h    = t & 255;
        const int half = t >> 8;
        float w[16];
        #pragma unroll
        for (int j = 0; j < 16; ++j)
            w[j] = ldsW[(half * 16 + j) * 256 + h];

        __syncthreads();   // b2: all f32 reads done before bf16 overwrite

        const int base = ((h >> 4) * 512) + ((h & 15) * 8); // shorts
        #pragma unroll
        for (int qq = 0; qq < 2; ++qq) {
            const int q = half * 2 + qq;      // q-block q covers k=q*8..q*8+7
            union { int4v iv; short8 s; } u;
            #pragma unroll
            for (int e = 0; e < 4; ++e)
                u.iv[e] = pkbf(w[qq * 8 + 2 * e], w[qq * 8 + 2 * e + 1]);
            *(short8*)&ldsB[base + q * 128] = u.s;
        }
    }

    __syncthreads();   // b3: ldsB ready

    // ---- 4) Compute: 8 tile-pairs for this wave's single m-tile ----
    float pacc[4][2];
    #pragma unroll
    for (int r = 0; r < 4; ++r)
        pacc[r][0] = pacc[r][1] = 0.0f;

    #pragma unroll
    for (int p = 0; p < 8; ++p) {
        short8 bfA = *(short8*)&ldsB[(p * 64 + lane) * 8];
        short8 bfB = *(short8*)&ldsB[((p + 8) * 64 + lane) * 8];
        float4 prm = ldsP[p * 16 + m];   // {bias_a, bias_b, w2a, w2b}, h=p*16+m

        floatx4 z = {0.0f, 0.0f, 0.0f, 0.0f};
        floatx4 xa = __builtin_amdgcn_mfma_f32_16x16x32_bf16(afrag, bfA, z, 0, 0, 0);
        floatx4 xb = __builtin_amdgcn_mfma_f32_16x16x32_bf16(afrag, bfB, z, 0, 0, 0);
        #pragma unroll
        for (int r = 0; r < 4; ++r) {
            float a   = xa[r] + prm.x;
            float g   = xb[r] + prm.y;
            float glu = a * sigmoidf(g);
            pacc[r][0] += glu * prm.z;
            pacc[r][1] += glu * prm.w;
        }
    }

    // ---- 5) Reduce across the 16 lanes of each quad; epilogue GLU ----
    #pragma unroll
    for (int r = 0; r < 4; ++r) {
        float s0 = pacc[r][0];
        float s1 = pacc[r][1];
        s0 += __shfl_xor(s0, 1);  s1 += __shfl_xor(s1, 1);
        s0 += __shfl_xor(s0, 2);  s1 += __shfl_xor(s1, 2);
        s0 += __shfl_xor(s0, 4);  s1 += __shfl_xor(s1, 4);
        s0 += __shfl_xor(s0, 8);  s1 += __shfl_xor(s1, 8);
        if (m == 0) {
            const int b = wv * 16 + quad * 4 + r;
            float x0 = s0 + bb0;
            float x1 = s1 + bb1;
            ldsO[b] = x0 * sigmoidf(x1) * invT;
        }
    }

    __syncthreads();

    // One coalesced 512B row into out_t (2048,128).
    if (t < 128)
        out_t[(size_t)n * 128 + t] = ldsO[t];
}

// Transpose out_t (2048,128) -> out (128,2048). 32x32 tiles, 256 blocks.
__global__ __launch_bounds__(256)
void transpose_kernel(const float* __restrict__ out_t, float* __restrict__ out)
{
    __shared__ float tile[32][33];
    const int t    = threadIdx.x;
    const int bidx = blockIdx.x;           // 0..255
    const int n0   = (bidx & 63) * 32;     // 64 n-tiles
    const int b0   = (bidx >> 6) * 32;     // 4 b-tiles

    const int tx = t & 31;
    const int ty = t >> 5;                 // 0..7

    #pragma unroll
    for (int i = 0; i < 4; ++i) {
        const int nl = ty + i * 8;
        tile[nl][tx] = out_t[(size_t)(n0 + nl) * 128 + b0 + tx];
    }

    __syncthreads();

    #pragma unroll
    for (int i = 0; i < 4; ++i) {
        const int bl = ty + i * 8;
        out[(size_t)(b0 + bl) * NN + n0 + tx] = tile[tx][bl];
    }
}

extern "C" void kernel_launch(void* const* d_in, const int* in_sizes, int n_in,
                              void* d_out, int out_size, void* d_ws, size_t ws_size,
                              hipStream_t stream) {
    const float* st = (const float*)d_in[0];
    const float* w1 = (const float*)d_in[1];
    const float* b1 = (const float*)d_in[2];
    const float* w2 = (const float*)d_in[3];
    const float* b2 = (const float*)d_in[4];
    const float* T  = (const float*)d_in[5];
    float* out   = (float*)d_out;
    float* out_t = (float*)d_ws;    // 2048*128*4 = 1 MB scratch

    nlm_kernel<<<dim3(NN), dim3(512), 0, stream>>>(st, w1, b1, w2, b2, T, out_t);
    transpose_kernel<<<dim3(256), dim3(256), 0, stream>>>(out_t, out);
}

// Round 9
// 155.021 us; speedup vs baseline: 1.7352x; 1.7352x over previous
//
#include <hip/hip_runtime.h>
#include <hip/hip_bf16.h>

// BatchedNLM: per-neuron 2-layer GLU MLP.
//   state_trace (128,2048,32) f32, fc1_w (2048,32,256), fc1_b (2048,256),
//   fc2_w (2048,128,2), fc2_b (2048,2), T (1)  ->  out (128,2048) f32
//
// R5 WIN (94->46): w1 via global_load_lds (async DMA). R6 WIN (46->40): rcpf
// sigmoid + LDS alias. R7 NEUTRAL: intra-block pipeline, LDS 55K killed occ.
// R8 FAILED: (512,6) -> VGPR cap 40 -> 250 MB spills. Empirical: VGPR cap
// ~= 256/arg2; tight caps always spilled. Lesson: loose caps only.
//
// R9: the in-kernel W1 f32->bf16-fragment transform was the structural tax
// (32 KB LDS, 3 barrier drains, ~160 VALU/thread). Split it out:
//   prep_kernel: w1 -> frag-major bf16 table in d_ws (pure streaming,
//     coalesced reads, no LDS). 33.5 MB, L2/L3-resident for main.
//   nlm_kernel:  B-frags via DIRECT coalesced global_load_dwordx4 (one wave
//     = 64 x 16 B contiguous = 1 KB/instr). No ldsW/DMA/convert; LDS 2.5 KB;
//     NO barrier in the p-loop -> compiler pipelines loads across MFMAs with
//     fine-grained vmcnt (the AITER pattern a barrier structure can't do).
//   transpose_kernel: unchanged (out_t -> out).

#define NN 2048

typedef __attribute__((ext_vector_type(8))) short short8;
typedef __attribute__((ext_vector_type(4))) float floatx4;
typedef __attribute__((ext_vector_type(4))) int int4v;

static __device__ __forceinline__ unsigned int pkbf(float a, float b) {
    __hip_bfloat162 h = __float22bfloat162_rn(make_float2(a, b));  // v_cvt_pk_bf16_f32
    return *(unsigned int*)&h;
}

static __device__ __forceinline__ float sigmoidf(float x) {
    return __builtin_amdgcn_rcpf(1.0f + __expf(-x));   // no IEEE div sequence
}

// ---- prep: w1 (n,32,256) f32 -> frag-major bf16 [n][p(16)][lane(64)][j(8)] ----
// One block per neuron; thread t owns column h=t. Reads: 32 coalesced 1-KB
// rows per block. Writes: 4 x 16 B per thread, contiguous 256 B per (p,q)
// group across 16 threads. No LDS, no barriers — pure streaming.
__global__ __launch_bounds__(256)
void prep_kernel(const float* __restrict__ w1, short* __restrict__ w1bf)
{
    const int n = blockIdx.x;
    const int t = threadIdx.x;                  // column h
    const float* src = w1 + (size_t)n * 8192 + t;
    short* dst = w1bf + (size_t)n * 8192;
    const int p = t >> 4;
    const int m = t & 15;
    #pragma unroll
    for (int q = 0; q < 4; ++q) {               // k-quad: k = q*8 + j
        float w[8];
        #pragma unroll
        for (int j = 0; j < 8; ++j)
            w[j] = src[(q * 8 + j) * 256];
        union { int4v iv; short8 s; } u;
        #pragma unroll
        for (int e = 0; e < 4; ++e)
            u.iv[e] = pkbf(w[2 * e], w[2 * e + 1]);
        *(short8*)&dst[(p * 64 + q * 16 + m) * 8] = u.s;   // lane = q*16+m
    }
}

// ---- main: one block (4 waves) per neuron; wave wv owns batches [32wv,32wv+32).
// GEMM1: mfma_f32_16x16x32_bf16, K=32 in one MFMA, acc from 0. GLU1 pairs
// (h, h+128) = tiles (p, p+8): same lane/reg -> register-only. fc2 (K=128,N=2)
// folded as per-lane partials + shfl_xor tree over the 16 lanes of each quad.
__global__ __launch_bounds__(256, 2)
void nlm_kernel(const float* __restrict__ st,
                const short* __restrict__ w1bf,
                const float* __restrict__ b1,
                const float* __restrict__ w2,
                const float* __restrict__ b2,
                const float* __restrict__ Tp,
                float* __restrict__ out_t)
{
    const int n = blockIdx.x;
    const int t = threadIdx.x;

    __shared__ float4 ldsP[128];   // {b1[h], b1[128+h], w2[2h], w2[2h+1]}
    __shared__ float  ldsO[128];

    const int lane = t & 63;
    const int wv   = t >> 6;      // wave 0..3
    const int m    = lane & 15;   // A row / C col
    const int quad = lane >> 4;   // k-quad / C row group

    // A fragments: A[m][k] = st[b][n][k], k = quad*8 + j (contiguous 32 B).
    floatx4 av[2][2];
    #pragma unroll
    for (int bt = 0; bt < 2; ++bt) {
        const int b = wv * 32 + bt * 16 + m;
        const float* sp = st + (size_t)b * (NN * 32) + (size_t)n * 32 + quad * 8;
        av[bt][0] = *(const floatx4*)sp;
        av[bt][1] = *(const floatx4*)(sp + 4);
    }

    // Param table (coalesced, threads 0..127).
    if (t < 128) {
        const float* b1p = b1 + n * 256;
        const float* w2p = w2 + n * 256;
        float  pa = b1p[t];
        float  pb = b1p[128 + t];
        float2 pw = *(const float2*)(w2p + 2 * t);
        ldsP[t] = make_float4(pa, pb, pw.x, pw.y);
    }

    const float bb0  = b2[n * 2 + 0];
    const float bb1  = b2[n * 2 + 1];
    const float invT = 1.0f / Tp[0];

    short8 afrag[2];
    #pragma unroll
    for (int bt = 0; bt < 2; ++bt) {
        union { int4v iv; short8 s; } u;
        u.iv[0] = pkbf(av[bt][0][0], av[bt][0][1]);
        u.iv[1] = pkbf(av[bt][0][2], av[bt][0][3]);
        u.iv[2] = pkbf(av[bt][1][0], av[bt][1][1]);
        u.iv[3] = pkbf(av[bt][1][2], av[bt][1][3]);
        afrag[bt] = u.s;
    }

    __syncthreads();   // ldsP visible (only barrier before epilogue)

    // B fragments streamed straight from the frag-major table: per tile p the
    // wave reads 64 lanes x 16 B = 1 KB contiguous. Prefetch-next structure;
    // no barriers -> loads stay in flight across MFMAs (vmcnt-pipelined).
    const short* wb = w1bf + (size_t)n * 8192;

    float pacc[2][4][2];
    #pragma unroll
    for (int bt = 0; bt < 2; ++bt)
        #pragma unroll
        for (int r = 0; r < 4; ++r)
            pacc[bt][r][0] = pacc[bt][r][1] = 0.0f;

    short8 nA = *(const short8*)&wb[(0 * 64 + lane) * 8];
    short8 nB = *(const short8*)&wb[(8 * 64 + lane) * 8];

    #pragma unroll
    for (int p = 0; p < 8; ++p) {
        short8 bfA = nA;
        short8 bfB = nB;
        if (p < 7) {
            nA = *(const short8*)&wb[((p + 1) * 64 + lane) * 8];
            nB = *(const short8*)&wb[((p + 9) * 64 + lane) * 8];
        }
        float4 prm = ldsP[p * 16 + m];   // {bias_a, bias_b, w2a, w2b}, h=p*16+m

        #pragma unroll
        for (int bt = 0; bt < 2; ++bt) {
            floatx4 z = {0.0f, 0.0f, 0.0f, 0.0f};
            floatx4 xa = __builtin_amdgcn_mfma_f32_16x16x32_bf16(afrag[bt], bfA, z, 0, 0, 0);
            floatx4 xb = __builtin_amdgcn_mfma_f32_16x16x32_bf16(afrag[bt], bfB, z, 0, 0, 0);
            #pragma unroll
            for (int r = 0; r < 4; ++r) {
                float a   = xa[r] + prm.x;
                float g   = xb[r] + prm.y;
                float glu = a * sigmoidf(g);
                pacc[bt][r][0] += glu * prm.z;
                pacc[bt][r][1] += glu * prm.w;
            }
        }
    }

    // Reduce fc2 partials across the 16 lanes of each quad; epilogue GLU.
    #pragma unroll
    for (int bt = 0; bt < 2; ++bt) {
        #pragma unroll
        for (int r = 0; r < 4; ++r) {
            float s0 = pacc[bt][r][0];
            float s1 = pacc[bt][r][1];
            s0 += __shfl_xor(s0, 1);  s1 += __shfl_xor(s1, 1);
            s0 += __shfl_xor(s0, 2);  s1 += __shfl_xor(s1, 2);
            s0 += __shfl_xor(s0, 4);  s1 += __shfl_xor(s1, 4);
            s0 += __shfl_xor(s0, 8);  s1 += __shfl_xor(s1, 8);
            if (m == 0) {
                const int b = wv * 32 + bt * 16 + quad * 4 + r;
                float x0 = s0 + bb0;
                float x1 = s1 + bb1;
                ldsO[b] = x0 * sigmoidf(x1) * invT;
            }
        }
    }

    __syncthreads();

    // One coalesced 512B row per block into out_t (2048,128).
    if (t < 128)
        out_t[(size_t)n * 128 + t] = ldsO[t];
}

// Transpose out_t (2048,128) -> out (128,2048). 32x32 tiles, 256 blocks.
__global__ __launch_bounds__(256)
void transpose_kernel(const float* __restrict__ out_t, float* __restrict__ out)
{
    __shared__ float tile[32][33];
    const int t    = threadIdx.x;
    const int bidx = blockIdx.x;           // 0..255
    const int n0   = (bidx & 63) * 32;     // 64 n-tiles
    const int b0   = (bidx >> 6) * 32;     // 4 b-tiles

    const int tx = t & 31;
    const int ty = t >> 5;                 // 0..7

    #pragma unroll
    for (int i = 0; i < 4; ++i) {
        const int nl = ty + i * 8;
        tile[nl][tx] = out_t[(size_t)(n0 + nl) * 128 + b0 + tx];
    }

    __syncthreads();

    #pragma unroll
    for (int i = 0; i < 4; ++i) {
        const int bl = ty + i * 8;
        out[(size_t)(b0 + bl) * NN + n0 + tx] = tile[tx][bl];
    }
}

extern "C" void kernel_launch(void* const* d_in, const int* in_sizes, int n_in,
                              void* d_out, int out_size, void* d_ws, size_t ws_size,
                              hipStream_t stream) {
    const float* st = (const float*)d_in[0];
    const float* w1 = (const float*)d_in[1];
    const float* b1 = (const float*)d_in[2];
    const float* w2 = (const float*)d_in[3];
    const float* b2 = (const float*)d_in[4];
    const float* T  = (const float*)d_in[5];
    float* out   = (float*)d_out;
    float* out_t = (float*)d_ws;                          // 1 MB
    short* w1bf  = (short*)((char*)d_ws + (1 << 20));     // 33.5 MB frag-major bf16

    prep_kernel<<<dim3(NN), dim3(256), 0, stream>>>(w1, w1bf);
    nlm_kernel<<<dim3(NN), dim3(256), 0, stream>>>(st, w1bf, b1, w2, b2, T, out_t);
    transpose_kernel<<<dim3(256), dim3(256), 0, stream>>>(out_t, out);
}